// Round 11
// baseline (675.628 us; speedup 1.0000x reference)
//
#include <hip/hip_runtime.h>
#include <hip/hip_bf16.h>

#define B_    16
#define CI_   512
#define CO_   128
#define QS    64
#define NWAVE 16
#define IPW   (CI_ / NWAVE)   // 32 capsules_in per wave

static constexpr float LAMB = 0.2f;
// exp(-0.5*x) == exp2f(x * NEG_HALF_LOG2E)
static constexpr float NEG_HALF_LOG2E = -0.72134752044448170368f;

// ---------- DPP pair-sum (VALU pipe) ----------
template <int CTRL>
__device__ __forceinline__ float dpp_add(float v) {
    int x = __builtin_bit_cast(int, v);
    int y = __builtin_amdgcn_update_dpp(x, x, CTRL, 0xF, 0xF, false);
    return v + __builtin_bit_cast(float, y);
}

__device__ __forceinline__ float wave_sum64_shfl(float v) {
#pragma unroll
    for (int m = 32; m >= 1; m >>= 1) v += __shfl_xor(v, m, 64);
    return v;
}

// ---------- transpose pass (R22: vectorized, gather form) ----------
// Both permutations are row-preserving 8x8 transposes within each 64-float
// row: out[k] = in[(k&7)*8 + (k>>3)].  Thread handles output float4 #base4:
// out positions k = 4u+j (u = base4&15) -> in positions 32(u&1) + 8j + (u>>1).
// Blocks [0,4096): trans->TT [i,o,s,p].  Blocks [4096,4608): pose->poseT.
__global__ __launch_bounds__(256) void transpose_kernel(
    const float* __restrict__ pose, const float* __restrict__ trans,
    float* __restrict__ poseT, float* __restrict__ TT)
{
    const int bid    = blockIdx.x;
    const bool isPose = bid >= 4096;
    const float* __restrict__ src = isPose ? pose  : trans;
    float*       __restrict__ dst = isPose ? poseT : TT;
    const int base4 = (isPose ? bid - 4096 : bid) * 256 + threadIdx.x;
    const int u     = base4 & 15;
    const int m0    = ((base4 >> 4) << 6) + ((u & 1) << 5) + (u >> 1);
    float4 v;
    v.x = src[m0];
    v.y = src[m0 + 8];
    v.z = src[m0 + 16];
    v.w = src[m0 + 24];
    ((float4*)dst)[base4] = v;
}

// ---------- fused 3-iteration EM, PERSISTENT (R25) ----------
// LEDGER (all closed with counter evidence):
//   R15/R16/R18: occupancy DEAD (waves/EU=floor(256/VGPR); V[32] reg-cache
//     forces 1x1024t block/CU). R17: LDS atomics -42us. R20: tree reduce
//     NEUTRAL (reduce hidden). R21: imm-offset TT -> load clustering spill.
//     R23: fused softmax -> fence perturbation -35us.
//   R19 (persistence) FAILED via a DIAGNOSED mechanism: pre-RA scheduler
//     hoisted pair k+1's 16 float4 loads above pair k's last V use ->
//     V[32]+64 load-dest VGPRs coexist -> spill each pair (WRITE 224MB =
//     exactly 128B/thread/pair).
// R25 re-opens R19 with the documented fix: #pragma unroll 1 +
//   __builtin_amdgcn_sched_barrier(0) as the LAST statement of each pair
//   iteration — a hard scheduling-region boundary the pre-RA scheduler
//   cannot move loads across -> live ranges disjoint -> no spill, while
//   keeping the win: no 7x(16-wave drain + redispatch + cold sweep-1 ramp)
//   per CU. o fixed per block (XCD x owns o in [16x,16x+16) -> TT slice
//   L2-hot, tT4 loop-invariant); b advances per pair. Cross-pair LDS
//   hazards covered by R20's barrier analysis (sAB/sAB2 disjoint; pair-k
//   reads complete before any pair-k+1 write passes syncA).
// TRIPWIRES: WRITE_SIZE must stay ~0.6MB, FETCH ~16.6MB; else revert to R24.
__global__
__attribute__((amdgpu_flat_work_group_size(1024, 1024), amdgpu_waves_per_eu(4, 8)))
void capsule_kernel(
    const float* __restrict__ poseT,   // [B,CI,q,p]
    const float* __restrict__ TT,      // [CI,CO,s,p]
    const float* __restrict__ act,
    const float* __restrict__ bias_a,
    const float* __restrict__ bias_b,
    float* __restrict__ logits,
    float* __restrict__ mu_out)
{
    const int bi  = blockIdx.x;               // 0..255, one per CU
    const int xcd = bi & 7;
    const int y   = bi >> 3;                  // 0..31
    const int o   = xcd * 16 + (y & 15);      // o fixed per block
    const int b0  = (y >> 4) * 8;             // b range [b0, b0+8)

    const int tid  = threadIdx.x;
    const int wave = tid >> 6;
    const int lane = tid & 63;
    const int q    = lane >> 3;
    const int s    = lane & 7;
    const int i0   = wave * IPW;

    // TT base: depends only on (i0,o,s) -> loop-invariant across pairs
    const float4* tT4 = (const float4*)TT + ((size_t)(i0 * CO_ + o)) * 16 + s * 2;

    __shared__ __align__(16) float prbuf[NWAVE][8 * 68];  // 8 rows x (64+4 pad)
    __shared__ __align__(16) float wbuf[NWAVE * 32];
    __shared__ __align__(16) float2 sAB [NWAVE][QS];      // packed (SwV,SwV2)
    __shared__ __align__(16) float2 sAB2[4][QS];          // level-1 partials
    __shared__ float sC [NWAVE];
    __shared__ float sC2[4];

    float* prw = prbuf[wave];

#pragma unroll 1
    for (int pair = 0; pair < 8; ++pair) {
        const int b = b0 + pair;
        const float4* pT4  = (const float4*)poseT + ((size_t)(b * CI_ + i0)) * 16 + q * 2;
        const float*  actb = act + b * CI_ + i0;

        float V[IPW];
        float Sw = 0.f, SwV = 0.f, SwV2 = 0.f;

        // sweep 1: fill V + act-weighted moments (w_i = act_i; R=1/CO cancels)
#pragma unroll
        for (int j = 0; j < IPW; ++j) {
            float4 a0 = pT4[j * 16];
            float4 a1 = pT4[j * 16 + 1];
            float4 b0v = tT4[(size_t)j * (CO_ * 16)];
            float4 b1v = tT4[(size_t)j * (CO_ * 16) + 1];
            float v;
            v = a0.x * b0v.x;
            v = fmaf(a0.y, b0v.y, v);
            v = fmaf(a0.z, b0v.z, v);
            v = fmaf(a0.w, b0v.w, v);
            v = fmaf(a1.x, b1v.x, v);
            v = fmaf(a1.y, b1v.y, v);
            v = fmaf(a1.z, b1v.z, v);
            v = fmaf(a1.w, b1v.w, v);
            V[j] = v;
            float ai = actb[j];
            Sw  += ai;
            SwV  = fmaf(ai, v, SwV);
            SwV2 = fmaf(ai * v, v, SwV2);
        }

        // two-level tree reduce, b64-packed (R20; disjoint in/out buffers make
        // the two in-reduce barriers sufficient, incl. across pairs).
        auto block_reduce = [&]() {
            sAB[wave][lane] = make_float2(SwV, SwV2);         // ds_write_b64
            if (lane == 0) sC[wave] = Sw;
            __syncthreads();                                  // syncA
            if (wave < 4) {
                float2 t0 = sAB[wave * 4 + 0][lane];
                float2 t1 = sAB[wave * 4 + 1][lane];
                float2 t2 = sAB[wave * 4 + 2][lane];
                float2 t3 = sAB[wave * 4 + 3][lane];
                float2 r;
                r.x = (t0.x + t1.x) + (t2.x + t3.x);
                r.y = (t0.y + t1.y) + (t2.y + t3.y);
                sAB2[wave][lane] = r;
                if (lane == 0)
                    sC2[wave] = (sC[wave * 4 + 0] + sC[wave * 4 + 1]) +
                                (sC[wave * 4 + 2] + sC[wave * 4 + 3]);
            }
            __syncthreads();                                  // syncB
            float2 u0 = sAB2[0][lane];
            float2 u1 = sAB2[1][lane];
            float2 u2 = sAB2[2][lane];
            float2 u3 = sAB2[3][lane];
            SwV  = (u0.x + u1.x) + (u2.x + u3.x);
            SwV2 = (u0.y + u1.y) + (u2.y + u3.y);
            Sw   = (sC2[0] + sC2[1]) + (sC2[2] + sC2[3]);
        };

        block_reduce();
        float invSw = (Sw != 0.f) ? 1.f / Sw : 0.f;
        float mu  = SwV * invSw;
        float var = fmaxf(fmaf(-mu, mu, SwV2 * invSw), 1e-30f);
        float is  = 1.f / sqrtf(var);

        // sweeps 2,3: w_j = a_j * E_j, E_j = sum_qs exp2(-(V-mu)^2 is^2/(2ln2))
#pragma unroll 1
        for (int it = 0; it < 2; ++it) {
            const float cc = is * is * NEG_HALF_LOG2E;
#pragma unroll
            for (int p = 0; p < 4; ++p) {
                // stage pr for 8 j's (per-wave private tile; DS in-order/wave)
#pragma unroll
                for (int jj = 0; jj < 8; ++jj) {
                    float d = V[p * 8 + jj] - mu;
                    prw[jj * 68 + lane] = exp2f(d * cc * d);
                }
                // row-sum: lane handles row r = lane>>3, slice (lane&7)*8..+7
                const int r  = lane >> 3;
                const int co = (lane & 7) * 8;
                const float4* rp = (const float4*)&prw[r * 68 + co];
                float4 x0 = rp[0], x1 = rp[1];
                float ps = ((x0.x + x0.y) + (x0.z + x0.w)) +
                           ((x1.x + x1.y) + (x1.z + x1.w));
                ps = dpp_add<0xB1>(ps);    // xor1
                ps = dpp_add<0x4E>(ps);    // xor2
                ps = dpp_add<0x141>(ps);   // row_half_mirror == xor4 after 1,2
                float wj = actb[p * 8 + r] * ps;     // full E_j on all 8 lanes
                if ((lane & 7) == 0) wbuf[wave * 32 + p * 8 + r] = wj;
            }
            // accumulate from the 32 broadcast w's
            const float4* wb4 = (const float4*)&wbuf[wave * 32];
            Sw = 0.f; SwV = 0.f; SwV2 = 0.f;
#pragma unroll
            for (int k = 0; k < 8; ++k) {
                float4 w4 = wb4[k];
                float v0 = V[4 * k + 0], v1 = V[4 * k + 1];
                float v2 = V[4 * k + 2], v3 = V[4 * k + 3];
                Sw += w4.x; SwV = fmaf(w4.x, v0, SwV); SwV2 = fmaf(w4.x * v0, v0, SwV2);
                Sw += w4.y; SwV = fmaf(w4.y, v1, SwV); SwV2 = fmaf(w4.y * v1, v1, SwV2);
                Sw += w4.z; SwV = fmaf(w4.z, v2, SwV); SwV2 = fmaf(w4.z * v2, v2, SwV2);
                Sw += w4.w; SwV = fmaf(w4.w, v3, SwV); SwV2 = fmaf(w4.w * v3, v3, SwV2);
            }
            block_reduce();
            invSw = (Sw != 0.f) ? 1.f / Sw : 0.f;
            mu  = SwV * invSw;
            var = fmaxf(fmaf(-mu, mu, SwV2 * invSw), 1e-30f);
            is  = 1.f / sqrtf(var);
        }

        if (wave == 0) {
            mu_out[((size_t)b * CO_ + o) * QS + lane] = mu;
            float sl = wave_sum64_shfl(0.5f * logf(var));
            if (lane == 0)
                logits[b * CO_ + o] = LAMB * (bias_a[o] - bias_b[o] - sl);
        }
        // Hard scheduling fence: forbid next pair's loads from hoisting above
        // this pair's last V use (R19's spill mechanism). Waves still overlap
        // across the fence at RUNTIME (it is a compile-time region boundary,
        // not a barrier) — wave w enters pair+1 sweep-1 as soon as it gets here.
        __builtin_amdgcn_sched_barrier(0);
    }
}

// ---------- legacy path (R9, proven): used only if ws_size is too small ----------
__global__ __launch_bounds__(256, 4) void capsule_legacy(
    const float* __restrict__ pose,
    const float* __restrict__ trans,
    const float* __restrict__ act,
    const float* __restrict__ bias_a,
    const float* __restrict__ bias_b,
    float* __restrict__ logits,
    float* __restrict__ mu_out)
{
    const int blk  = blockIdx.x;
    const int b    = blk >> 7;
    const int o    = blk & 127;
    const int tid  = threadIdx.x;
    const int wave = tid >> 6;
    const int lane = tid & 63;
    const int q    = lane >> 3;
    const int s    = lane & 7;
    const int i0   = wave * 128;

    const float* poseb = pose + ((size_t)b * CI_ + i0) * QS + lane;
    const float* tb    = trans + ((size_t)i0 * CO_ + o) * QS + lane;
    const float* actb  = act + b * CI_ + i0;

    __shared__ float sSwV[4][QS];
    __shared__ float sSwV2[4][QS];
    __shared__ float sSw[4];

    float Sw = 0.f, SwV = 0.f, SwV2 = 0.f;

    auto do_sweep = [&](bool use_prob, float mu_r, float is_r) {
        Sw = 0.f; SwV = 0.f; SwV2 = 0.f;
        for (int j = 0; j < 128; ++j) {
            float pe = poseb[(size_t)j * QS];
            float te = tb[(size_t)j * (CO_ * QS)];
            float ai = actb[j];
            float V = 0.f;
#pragma unroll
            for (int p = 0; p < 8; ++p) {
                float a = __shfl(pe, p * 8 + q, 64);
                float t = __shfl(te, p * 8 + s, 64);
                V = fmaf(a, t, V);
            }
            float w;
            if (use_prob) {
                float d  = V - mu_r;
                float e  = d * is_r;
                float pr = is_r * exp2f(e * e * NEG_HALF_LOG2E);
                w = ai * wave_sum64_shfl(pr);
            } else {
                w = ai;
            }
            Sw += w;
            SwV  = fmaf(w, V, SwV);
            SwV2 = fmaf(w * V, V, SwV2);
        }
        __syncthreads();
        sSwV[wave][lane]  = SwV;
        sSwV2[wave][lane] = SwV2;
        if (lane == 0) sSw[wave] = Sw;
        __syncthreads();
        float a = 0.f, c = 0.f, d2 = 0.f;
#pragma unroll
        for (int w2 = 0; w2 < 4; ++w2) {
            a  += sSwV[w2][lane];
            d2 += sSwV2[w2][lane];
            c  += sSw[w2];
        }
        SwV = a; SwV2 = d2; Sw = c;
    };

    float mu = 0.f, var = 1.f, is = 1.f;
    do_sweep(false, 0.f, 0.f);
    {
        float invSw = (Sw != 0.f) ? 1.f / Sw : 0.f;
        mu = SwV * invSw; var = fmaxf(fmaf(-mu, mu, SwV2 * invSw), 1e-30f);
        is = 1.f / sqrtf(var);
    }
    do_sweep(true, mu, is);
    {
        float invSw = (Sw != 0.f) ? 1.f / Sw : 0.f;
        mu = SwV * invSw; var = fmaxf(fmaf(-mu, mu, SwV2 * invSw), 1e-30f);
        is = 1.f / sqrtf(var);
    }
    do_sweep(true, mu, is);
    {
        float invSw = (Sw != 0.f) ? 1.f / Sw : 0.f;
        mu = SwV * invSw; var = fmaxf(fmaf(-mu, mu, SwV2 * invSw), 1e-30f);
    }

    if (wave == 0) {
        mu_out[((size_t)b * CO_ + o) * QS + lane] = mu;
        float sl = wave_sum64_shfl(0.5f * logf(var));
        if (lane == 0)
            logits[b * CO_ + o] = LAMB * (bias_a[o] - bias_b[o] - sl);
    }
}

__global__ __launch_bounds__(128) void softmax_kernel(
    const float* __restrict__ logits, float* __restrict__ out)
{
    const int b = blockIdx.x;
    const int t = threadIdx.x;
    float l = logits[b * CO_ + t];

    __shared__ float sm[2];
    __shared__ float s2[2];

    float m = l;
#pragma unroll
    for (int k = 32; k >= 1; k >>= 1) m = fmaxf(m, __shfl_xor(m, k, 64));
    if ((t & 63) == 0) sm[t >> 6] = m;
    __syncthreads();
    m = fmaxf(sm[0], sm[1]);

    float e = expf(l - m);
    float ssum = e;
#pragma unroll
    for (int k = 32; k >= 1; k >>= 1) ssum += __shfl_xor(ssum, k, 64);
    if ((t & 63) == 0) s2[t >> 6] = ssum;
    __syncthreads();
    float tot = s2[0] + s2[1];

    out[b * CO_ + t] = e / tot;
}

extern "C" void kernel_launch(void* const* d_in, const int* in_sizes, int n_in,
                              void* d_out, int out_size, void* d_ws, size_t ws_size,
                              hipStream_t stream) {
    // Size-keyed binding (no-op under documented order; sizes are all distinct).
    const float *act = nullptr, *pose = nullptr, *trans = nullptr;
    const float *bias_a = nullptr, *bias_b = nullptr;
    for (int i = 0; i < n_in; ++i) {
        const float* p = (const float*)d_in[i];
        switch (in_sizes[i]) {
            case 8192:    act = p; break;
            case 524288:  pose = p; break;
            case 4194304: trans = p; break;
            case 128:     if (!bias_a) bias_a = p; else bias_b = p; break;
            default: break;
        }
    }
    if (!act || !pose || !trans || !bias_a || !bias_b) {
        act    = (const float*)d_in[0];
        pose   = (const float*)d_in[1];
        trans  = (const float*)d_in[2];
        bias_a = (const float*)d_in[3];
        bias_b = (const float*)d_in[4];
    }

    float* out_act = (float*)d_out;                // f32 [16,128]
    float* out_mu  = out_act + B_ * CO_;           // f32 [16,128,8,8]

    const size_t NEEDED = (size_t)(524288 + 4194304 + 2048) * 4;   // ~18.9 MB

    if (ws_size >= NEEDED) {
        float* poseT  = (float*)d_ws;              // 524288
        float* TT     = poseT + 524288;            // 4194304
        float* logits = TT + 4194304;              // 2048

        // 4096 blocks for trans (1,048,576 float4s) + 512 for pose (131,072)
        transpose_kernel<<<dim3(4608), dim3(256), 0, stream>>>(
            pose, trans, poseT, TT);
        capsule_kernel<<<dim3(256), dim3(1024), 0, stream>>>(
            poseT, TT, act, bias_a, bias_b, logits, out_mu);
        softmax_kernel<<<dim3(B_), dim3(128), 0, stream>>>(logits, out_act);
    } else {
        float* logits = (float*)d_ws;              // 2048 floats
        capsule_legacy<<<dim3(B_ * CO_), dim3(256), 0, stream>>>(
            pose, trans, act, bias_a, bias_b, logits, out_mu);
        softmax_kernel<<<dim3(B_), dim3(128), 0, stream>>>(logits, out_act);
    }
}

// Round 12
// 273.813 us; speedup vs baseline: 2.4675x; 2.4675x over previous
//
#include <hip/hip_runtime.h>
#include <hip/hip_bf16.h>

#define B_    16
#define CI_   512
#define CO_   128
#define QS    64
#define NWAVE 16
#define IPW   (CI_ / NWAVE)   // 32 capsules_in per wave

static constexpr float LAMB = 0.2f;
// exp(-0.5*x) == exp2f(x * NEG_HALF_LOG2E)
static constexpr float NEG_HALF_LOG2E = -0.72134752044448170368f;

// ---------- DPP pair-sum (VALU pipe) ----------
template <int CTRL>
__device__ __forceinline__ float dpp_add(float v) {
    int x = __builtin_bit_cast(int, v);
    int y = __builtin_amdgcn_update_dpp(x, x, CTRL, 0xF, 0xF, false);
    return v + __builtin_bit_cast(float, y);
}

__device__ __forceinline__ float wave_sum64_shfl(float v) {
#pragma unroll
    for (int m = 32; m >= 1; m >>= 1) v += __shfl_xor(v, m, 64);
    return v;
}

// ---------- transpose pass (R22: vectorized, gather form) ----------
// Both permutations are row-preserving 8x8 transposes within each 64-float
// row: out[k] = in[(k&7)*8 + (k>>3)].  Thread handles output float4 #base4:
// out positions k = 4u+j (u = base4&15) -> in positions 32(u&1) + 8j + (u>>1)
// (imm-offset foldable: +0/+32/+64/+96 bytes). 4 scalar gathers + one
// perfectly-coalesced float4 store; no LDS, no barrier.
// Blocks [0,4096): trans->TT [i,o,s,p].  Blocks [4096,4608): pose->poseT.
__global__ __launch_bounds__(256) void transpose_kernel(
    const float* __restrict__ pose, const float* __restrict__ trans,
    float* __restrict__ poseT, float* __restrict__ TT)
{
    const int bid    = blockIdx.x;
    const bool isPose = bid >= 4096;
    const float* __restrict__ src = isPose ? pose  : trans;
    float*       __restrict__ dst = isPose ? poseT : TT;
    const int base4 = (isPose ? bid - 4096 : bid) * 256 + threadIdx.x;
    const int u     = base4 & 15;
    const int m0    = ((base4 >> 4) << 6) + ((u & 1) << 5) + (u >> 1);
    float4 v;
    v.x = src[m0];
    v.y = src[m0 + 8];
    v.z = src[m0 + 16];
    v.w = src[m0 + 24];
    ((float4*)dst)[base4] = v;
}

// ---------- fused 3-iteration EM (FINAL, measured best: 274.5us total) ----------
// One block per (b,o): 16 waves, wave w owns i in [w*32, w*32+32).
// V register-cached (full unroll -> SROA; R12 proved partial unroll spills).
// COMPLETE LEDGER (every branch closed with counter evidence):
//   R15/R16/R18: occupancy DEAD. waves/EU = floor(256/VGPR); 1024t blocks
//     quantize residency to whole blocks; 2 blocks/CU needs VGPR<=32 which
//     forces spill (R15) or V-recompute with serialized L2 chains (R18).
//   R17: LDS ds_add_f32 reduce serializes 16-way per address -> -42us.
//   R19/R25: persistence DEAD TWICE. The regalloc must hold V[32] live
//     across the runtime loop back-edge + barriers -> spills regardless of
//     sched_barrier(0) (which bounds instruction scheduling, NOT register
//     allocation). R25: FETCH 1.09GB, WRITE 264MB, 611us.
//   R20: 8x-leaner b64 tree reduce -> NEUTRAL; block_reduce is latency-hidden
//     behind resident waves. Kept (marginally fewer instrs, no cost).
//   R21: TT [o,i,s,p] imm-offset diet -> independent-load clustering, live-
//     range blowup, spill (WRITE 180MB). The 64-bit addr chains of [i,o,s,p]
//     are the de-facto load-motion throttle; layout kept as [i,o,s,p].
//   R23: fused last-block softmax -> device-fence + kernarg pressure slowed
//     the WHOLE kernel 35us (VALU 46->39.5) with zero spill.
// Plateau characterization: HBM 1%, VALU ~46%, occupancy 45% (structural),
// zero spill. Latency-structure-bound at 1 block/CU; every lever that could
// change the structure trips a codegen cliff (spill) that costs 3-10x the
// prospective gain.
__global__
__attribute__((amdgpu_flat_work_group_size(1024, 1024), amdgpu_waves_per_eu(4, 8)))
void capsule_kernel(
    const float* __restrict__ poseT,   // [B,CI,q,p]
    const float* __restrict__ TT,      // [CI,CO,s,p]
    const float* __restrict__ act,
    const float* __restrict__ bias_a,
    const float* __restrict__ bias_b,
    float* __restrict__ logits,
    float* __restrict__ mu_out)
{
    // XCD-aware swizzle: 16 o's pinned per XCD so its TT slice stays L2-hot.
    const int blk = blockIdx.x;
    const int xcd = blk & 7;
    const int idx = blk >> 3;                 // 0..255
    const int o   = xcd + ((idx & 15) << 3);
    const int b   = idx >> 4;

    const int tid  = threadIdx.x;
    const int wave = tid >> 6;
    const int lane = tid & 63;
    const int q    = lane >> 3;
    const int s    = lane & 7;
    const int i0   = wave * IPW;

    const float4* pT4  = (const float4*)poseT + ((size_t)(b * CI_ + i0)) * 16 + q * 2;
    const float4* tT4  = (const float4*)TT    + ((size_t)(i0 * CO_ + o)) * 16 + s * 2;
    const float*  actb = act + b * CI_ + i0;

    __shared__ __align__(16) float prbuf[NWAVE][8 * 68];  // 8 rows x (64+4 pad)
    __shared__ __align__(16) float wbuf[NWAVE * 32];
    __shared__ __align__(16) float2 sAB [NWAVE][QS];      // packed (SwV,SwV2)
    __shared__ __align__(16) float2 sAB2[4][QS];          // level-1 partials
    __shared__ float sC [NWAVE];
    __shared__ float sC2[4];

    float* prw = prbuf[wave];

    float V[IPW];
    float Sw = 0.f, SwV = 0.f, SwV2 = 0.f;

    // sweep 1: fill V + act-weighted moments (w_i = act_i; R=1/CO cancels)
#pragma unroll
    for (int j = 0; j < IPW; ++j) {
        float4 a0 = pT4[j * 16];
        float4 a1 = pT4[j * 16 + 1];
        float4 b0 = tT4[(size_t)j * (CO_ * 16)];
        float4 b1 = tT4[(size_t)j * (CO_ * 16) + 1];
        float v;
        v = a0.x * b0.x;
        v = fmaf(a0.y, b0.y, v);
        v = fmaf(a0.z, b0.z, v);
        v = fmaf(a0.w, b0.w, v);
        v = fmaf(a1.x, b1.x, v);
        v = fmaf(a1.y, b1.y, v);
        v = fmaf(a1.z, b1.z, v);
        v = fmaf(a1.w, b1.w, v);
        V[j] = v;
        float ai = actb[j];
        Sw  += ai;
        SwV  = fmaf(ai, v, SwV);
        SwV2 = fmaf(ai * v, v, SwV2);
    }

    // two-level tree reduce, b64-packed (R20; disjoint in/out buffers make the
    // two in-reduce barriers sufficient).
    auto block_reduce = [&]() {
        sAB[wave][lane] = make_float2(SwV, SwV2);         // ds_write_b64
        if (lane == 0) sC[wave] = Sw;
        __syncthreads();                                  // syncA
        if (wave < 4) {
            float2 t0 = sAB[wave * 4 + 0][lane];
            float2 t1 = sAB[wave * 4 + 1][lane];
            float2 t2 = sAB[wave * 4 + 2][lane];
            float2 t3 = sAB[wave * 4 + 3][lane];
            float2 r;
            r.x = (t0.x + t1.x) + (t2.x + t3.x);
            r.y = (t0.y + t1.y) + (t2.y + t3.y);
            sAB2[wave][lane] = r;
            if (lane == 0)
                sC2[wave] = (sC[wave * 4 + 0] + sC[wave * 4 + 1]) +
                            (sC[wave * 4 + 2] + sC[wave * 4 + 3]);
        }
        __syncthreads();                                  // syncB
        float2 u0 = sAB2[0][lane];
        float2 u1 = sAB2[1][lane];
        float2 u2 = sAB2[2][lane];
        float2 u3 = sAB2[3][lane];
        SwV  = (u0.x + u1.x) + (u2.x + u3.x);
        SwV2 = (u0.y + u1.y) + (u2.y + u3.y);
        Sw   = (sC2[0] + sC2[1]) + (sC2[2] + sC2[3]);
    };

    block_reduce();
    float invSw = (Sw != 0.f) ? 1.f / Sw : 0.f;
    float mu  = SwV * invSw;
    float var = fmaxf(fmaf(-mu, mu, SwV2 * invSw), 1e-30f);
    float is  = 1.f / sqrtf(var);

    // sweeps 2,3: w_j = a_j * E_j, E_j = sum_qs exp2(-(V-mu)^2 * is^2 / (2 ln2))
    // (act_out, L1 norm, 1/sqrt(2pi), and the uniform is-factor all cancel in r)
#pragma unroll 1
    for (int it = 0; it < 2; ++it) {
        const float cc = is * is * NEG_HALF_LOG2E;
#pragma unroll
        for (int p = 0; p < 4; ++p) {
            // stage pr for 8 j's (per-wave private tile; DS ops in-order per wave)
#pragma unroll
            for (int jj = 0; jj < 8; ++jj) {
                float d = V[p * 8 + jj] - mu;
                prw[jj * 68 + lane] = exp2f(d * cc * d);
            }
            // row-sum: lane handles row r = lane>>3, slice (lane&7)*8..+7
            const int r  = lane >> 3;
            const int co = (lane & 7) * 8;
            const float4* rp = (const float4*)&prw[r * 68 + co];
            float4 x0 = rp[0], x1 = rp[1];
            float ps = ((x0.x + x0.y) + (x0.z + x0.w)) +
                       ((x1.x + x1.y) + (x1.z + x1.w));
            ps = dpp_add<0xB1>(ps);    // xor1
            ps = dpp_add<0x4E>(ps);    // xor2
            ps = dpp_add<0x141>(ps);   // row_half_mirror == xor4 after 1,2
            float wj = actb[p * 8 + r] * ps;     // full E_j on all 8 lanes
            if ((lane & 7) == 0) wbuf[wave * 32 + p * 8 + r] = wj;
        }
        // accumulate from the 32 broadcast w's
        const float4* wb4 = (const float4*)&wbuf[wave * 32];
        Sw = 0.f; SwV = 0.f; SwV2 = 0.f;
#pragma unroll
        for (int k = 0; k < 8; ++k) {
            float4 w4 = wb4[k];
            float v0 = V[4 * k + 0], v1 = V[4 * k + 1];
            float v2 = V[4 * k + 2], v3 = V[4 * k + 3];
            Sw += w4.x; SwV = fmaf(w4.x, v0, SwV); SwV2 = fmaf(w4.x * v0, v0, SwV2);
            Sw += w4.y; SwV = fmaf(w4.y, v1, SwV); SwV2 = fmaf(w4.y * v1, v1, SwV2);
            Sw += w4.z; SwV = fmaf(w4.z, v2, SwV); SwV2 = fmaf(w4.z * v2, v2, SwV2);
            Sw += w4.w; SwV = fmaf(w4.w, v3, SwV); SwV2 = fmaf(w4.w * v3, v3, SwV2);
        }
        block_reduce();
        invSw = (Sw != 0.f) ? 1.f / Sw : 0.f;
        mu  = SwV * invSw;
        var = fmaxf(fmaf(-mu, mu, SwV2 * invSw), 1e-30f);
        is  = 1.f / sqrtf(var);
    }

    if (wave == 0) {
        mu_out[((size_t)b * CO_ + o) * QS + lane] = mu;
        // logits = LAMB*(bias_a - bias_b*1 - sum_qs 0.5*log var) + softmax-inv const
        float sl = wave_sum64_shfl(0.5f * logf(var));
        if (lane == 0)
            logits[b * CO_ + o] = LAMB * (bias_a[o] - bias_b[o] - sl);
    }
}

// ---------- legacy path (R9, proven): used only if ws_size is too small ----------
__global__ __launch_bounds__(256, 4) void capsule_legacy(
    const float* __restrict__ pose,
    const float* __restrict__ trans,
    const float* __restrict__ act,
    const float* __restrict__ bias_a,
    const float* __restrict__ bias_b,
    float* __restrict__ logits,
    float* __restrict__ mu_out)
{
    const int blk  = blockIdx.x;
    const int b    = blk >> 7;
    const int o    = blk & 127;
    const int tid  = threadIdx.x;
    const int wave = tid >> 6;
    const int lane = tid & 63;
    const int q    = lane >> 3;
    const int s    = lane & 7;
    const int i0   = wave * 128;

    const float* poseb = pose + ((size_t)b * CI_ + i0) * QS + lane;
    const float* tb    = trans + ((size_t)i0 * CO_ + o) * QS + lane;
    const float* actb  = act + b * CI_ + i0;

    __shared__ float sSwV[4][QS];
    __shared__ float sSwV2[4][QS];
    __shared__ float sSw[4];

    float Sw = 0.f, SwV = 0.f, SwV2 = 0.f;

    auto do_sweep = [&](bool use_prob, float mu_r, float is_r) {
        Sw = 0.f; SwV = 0.f; SwV2 = 0.f;
        for (int j = 0; j < 128; ++j) {
            float pe = poseb[(size_t)j * QS];
            float te = tb[(size_t)j * (CO_ * QS)];
            float ai = actb[j];
            float V = 0.f;
#pragma unroll
            for (int p = 0; p < 8; ++p) {
                float a = __shfl(pe, p * 8 + q, 64);
                float t = __shfl(te, p * 8 + s, 64);
                V = fmaf(a, t, V);
            }
            float w;
            if (use_prob) {
                float d  = V - mu_r;
                float e  = d * is_r;
                float pr = is_r * exp2f(e * e * NEG_HALF_LOG2E);
                w = ai * wave_sum64_shfl(pr);
            } else {
                w = ai;
            }
            Sw += w;
            SwV  = fmaf(w, V, SwV);
            SwV2 = fmaf(w * V, V, SwV2);
        }
        __syncthreads();
        sSwV[wave][lane]  = SwV;
        sSwV2[wave][lane] = SwV2;
        if (lane == 0) sSw[wave] = Sw;
        __syncthreads();
        float a = 0.f, c = 0.f, d2 = 0.f;
#pragma unroll
        for (int w2 = 0; w2 < 4; ++w2) {
            a  += sSwV[w2][lane];
            d2 += sSwV2[w2][lane];
            c  += sSw[w2];
        }
        SwV = a; SwV2 = d2; Sw = c;
    };

    float mu = 0.f, var = 1.f, is = 1.f;
    do_sweep(false, 0.f, 0.f);
    {
        float invSw = (Sw != 0.f) ? 1.f / Sw : 0.f;
        mu = SwV * invSw; var = fmaxf(fmaf(-mu, mu, SwV2 * invSw), 1e-30f);
        is = 1.f / sqrtf(var);
    }
    do_sweep(true, mu, is);
    {
        float invSw = (Sw != 0.f) ? 1.f / Sw : 0.f;
        mu = SwV * invSw; var = fmaxf(fmaf(-mu, mu, SwV2 * invSw), 1e-30f);
        is = 1.f / sqrtf(var);
    }
    do_sweep(true, mu, is);
    {
        float invSw = (Sw != 0.f) ? 1.f / Sw : 0.f;
        mu = SwV * invSw; var = fmaxf(fmaf(-mu, mu, SwV2 * invSw), 1e-30f);
    }

    if (wave == 0) {
        mu_out[((size_t)b * CO_ + o) * QS + lane] = mu;
        float sl = wave_sum64_shfl(0.5f * logf(var));
        if (lane == 0)
            logits[b * CO_ + o] = LAMB * (bias_a[o] - bias_b[o] - sl);
    }
}

__global__ __launch_bounds__(128) void softmax_kernel(
    const float* __restrict__ logits, float* __restrict__ out)
{
    const int b = blockIdx.x;
    const int t = threadIdx.x;
    float l = logits[b * CO_ + t];

    __shared__ float sm[2];
    __shared__ float s2[2];

    float m = l;
#pragma unroll
    for (int k = 32; k >= 1; k >>= 1) m = fmaxf(m, __shfl_xor(m, k, 64));
    if ((t & 63) == 0) sm[t >> 6] = m;
    __syncthreads();
    m = fmaxf(sm[0], sm[1]);

    float e = expf(l - m);
    float ssum = e;
#pragma unroll
    for (int k = 32; k >= 1; k >>= 1) ssum += __shfl_xor(ssum, k, 64);
    if ((t & 63) == 0) s2[t >> 6] = ssum;
    __syncthreads();
    float tot = s2[0] + s2[1];

    out[b * CO_ + t] = e / tot;
}

extern "C" void kernel_launch(void* const* d_in, const int* in_sizes, int n_in,
                              void* d_out, int out_size, void* d_ws, size_t ws_size,
                              hipStream_t stream) {
    // Size-keyed binding (no-op under documented order; sizes are all distinct).
    const float *act = nullptr, *pose = nullptr, *trans = nullptr;
    const float *bias_a = nullptr, *bias_b = nullptr;
    for (int i = 0; i < n_in; ++i) {
        const float* p = (const float*)d_in[i];
        switch (in_sizes[i]) {
            case 8192:    act = p; break;
            case 524288:  pose = p; break;
            case 4194304: trans = p; break;
            case 128:     if (!bias_a) bias_a = p; else bias_b = p; break;
            default: break;
        }
    }
    if (!act || !pose || !trans || !bias_a || !bias_b) {
        act    = (const float*)d_in[0];
        pose   = (const float*)d_in[1];
        trans  = (const float*)d_in[2];
        bias_a = (const float*)d_in[3];
        bias_b = (const float*)d_in[4];
    }

    float* out_act = (float*)d_out;                // f32 [16,128]
    float* out_mu  = out_act + B_ * CO_;           // f32 [16,128,8,8]

    const size_t NEEDED = (size_t)(524288 + 4194304 + 2048) * 4;   // ~18.9 MB

    if (ws_size >= NEEDED) {
        float* poseT  = (float*)d_ws;              // 524288
        float* TT     = poseT + 524288;            // 4194304
        float* logits = TT + 4194304;              // 2048

        // 4096 blocks for trans (1,048,576 float4s) + 512 for pose (131,072)
        transpose_kernel<<<dim3(4608), dim3(256), 0, stream>>>(
            pose, trans, poseT, TT);
        capsule_kernel<<<dim3(B_ * CO_), dim3(1024), 0, stream>>>(
            poseT, TT, act, bias_a, bias_b, logits, out_mu);
        softmax_kernel<<<dim3(B_), dim3(128), 0, stream>>>(logits, out_act);
    } else {
        float* logits = (float*)d_ws;              // 2048 floats
        capsule_legacy<<<dim3(B_ * CO_), dim3(256), 0, stream>>>(
            pose, trans, act, bias_a, bias_b, logits, out_mu);
        softmax_kernel<<<dim3(B_), dim3(128), 0, stream>>>(logits, out_act);
    }
}